// Round 1
// baseline (527.172 us; speedup 1.0000x reference)
//
#include <hip/hip_runtime.h>
#include <math.h>

#define N_NODES 50000
#define N_EDGES 800000
#define IN_DIM 256
#define HID 128

// ---------------------------------------------------------------------------
// Fused GEMM: C[M,128] = act( sum_s A_s @ W_s + bias0 (+bias1) )
// BM=64 rows/block, BN=128 (all cols), BK=32. 256 threads, each computes 4x8.
// W tile staged in LDS; A read direct from global (each element read once per
// block, float4, 16-lane broadcast). Optionally accumulates per-column
// sum/sumsq (for training-mode BatchNorm) via wave-shuffle + LDS + global atomics.
// ---------------------------------------------------------------------------
template<bool LEAKY, bool STATS>
__global__ __launch_bounds__(256) void gemm_fused(
    int M, int nsrc,
    const float* __restrict__ A0, int K0,
    const float* __restrict__ A1, int K1,
    const float* __restrict__ A2, int K2,
    const float* __restrict__ W0,
    const float* __restrict__ W1,
    const float* __restrict__ W2,
    const float* __restrict__ bias0,
    const float* __restrict__ bias1,
    float* __restrict__ C,
    float* __restrict__ stats)   // [256]: sum[0..127], sumsq[128..255]
{
    __shared__ float Ws[32][128];
    __shared__ float sred[256];

    const int t    = threadIdx.x;
    const int tr   = t >> 4;          // 0..15 (4 rows each)
    const int tc   = t & 15;          // 0..15 (8 cols each)
    const int row0 = blockIdx.x * 64 + tr * 4;
    const int col0 = tc * 8;

    float acc[4][8];
#pragma unroll
    for (int u = 0; u < 4; ++u)
#pragma unroll
        for (int v = 0; v < 8; ++v) acc[u][v] = 0.f;

    const float* Aarr[3] = {A0, A1, A2};
    const float* Warr[3] = {W0, W1, W2};
    const int    Karr[3] = {K0, K1, K2};

#pragma unroll
    for (int s = 0; s < 3; ++s) {
        if (s >= nsrc) break;
        const float* __restrict__ A = Aarr[s];
        const float* __restrict__ W = Warr[s];
        const int K = Karr[s];

        for (int k0 = 0; k0 < K; k0 += 32) {
            __syncthreads();
            // stage W chunk [32][128]: 1024 float4 / 256 threads = 4 each
#pragma unroll
            for (int i = 0; i < 4; ++i) {
                int idx = t + 256 * i;
                int kk  = idx >> 5;      // 0..31
                int g   = idx & 31;      // float4 group in row
                *reinterpret_cast<float4*>(&Ws[kk][g * 4]) =
                    *reinterpret_cast<const float4*>(&W[(size_t)(k0 + kk) * HID + g * 4]);
            }
            __syncthreads();

#pragma unroll
            for (int kk = 0; kk < 32; kk += 4) {
                float4 a4[4];
#pragma unroll
                for (int u = 0; u < 4; ++u) {
                    int r = row0 + u;
                    r = (r < M) ? r : (M - 1);   // clamp; stores/stats guarded later
                    a4[u] = *reinterpret_cast<const float4*>(&A[(size_t)r * K + k0 + kk]);
                }
#pragma unroll
                for (int q = 0; q < 4; ++q) {
                    float w[8];
#pragma unroll
                    for (int v = 0; v < 8; ++v) w[v] = Ws[kk + q][col0 + v];
#pragma unroll
                    for (int u = 0; u < 4; ++u) {
                        float a = (q == 0) ? a4[u].x : (q == 1) ? a4[u].y
                                 : (q == 2) ? a4[u].z : a4[u].w;
#pragma unroll
                        for (int v = 0; v < 8; ++v) acc[u][v] = fmaf(a, w[v], acc[u][v]);
                    }
                }
            }
        }
    }

    // epilogue: bias (+bias1), optional leaky, store, optional BN stats
    float b[8];
#pragma unroll
    for (int v = 0; v < 8; ++v) {
        float bb = bias0 ? bias0[col0 + v] : 0.f;
        if (bias1) bb += bias1[col0 + v];
        b[v] = bb;
    }

    float colsum[8], colsq[8];
#pragma unroll
    for (int v = 0; v < 8; ++v) { colsum[v] = 0.f; colsq[v] = 0.f; }

#pragma unroll
    for (int u = 0; u < 4; ++u) {
        int r = row0 + u;
        if (r < M) {
            float vals[8];
#pragma unroll
            for (int v = 0; v < 8; ++v) {
                float y = acc[u][v] + b[v];
                if (LEAKY) y = (y >= 0.f) ? y : 0.2f * y;
                vals[v] = y;
                if (STATS) { colsum[v] += y; colsq[v] += y * y; }
            }
            float4 s0 = {vals[0], vals[1], vals[2], vals[3]};
            float4 s1 = {vals[4], vals[5], vals[6], vals[7]};
            *reinterpret_cast<float4*>(&C[(size_t)r * HID + col0])     = s0;
            *reinterpret_cast<float4*>(&C[(size_t)r * HID + col0 + 4]) = s1;
        }
    }

    if (STATS) {
        sred[t] = 0.f;
        __syncthreads();
#pragma unroll
        for (int v = 0; v < 8; ++v) {
            float s = colsum[v];
            float q = colsq[v];
            s += __shfl_xor(s, 16); s += __shfl_xor(s, 32);
            q += __shfl_xor(q, 16); q += __shfl_xor(q, 32);
            if ((t & 48) == 0) {              // one lane per tc per wave
                atomicAdd(&sred[col0 + v], s);
                atomicAdd(&sred[128 + col0 + v], q);
            }
        }
        __syncthreads();
        atomicAdd(&stats[t], sred[t]);
    }
}

// ---------------------------------------------------------------------------
// BN param finalize: scale/shift per column
// ---------------------------------------------------------------------------
__global__ void bn_params(const float* __restrict__ stats,
                          const float* __restrict__ gamma,
                          const float* __restrict__ beta,
                          float* __restrict__ scale,
                          float* __restrict__ shift, float invn)
{
    int j = threadIdx.x;   // 128
    float mean = stats[j] * invn;
    float var  = stats[128 + j] * invn - mean * mean;
    var = fmaxf(var, 0.f);
    float sc = gamma[j] / sqrtf(var + 1e-5f);
    scale[j] = sc;
    shift[j] = beta[j] - mean * sc;
}

__global__ __launch_bounds__(256) void bn_apply(const float* __restrict__ in,
                                                float* __restrict__ out,
                                                const float* __restrict__ scale,
                                                const float* __restrict__ shift,
                                                int total4)
{
    int idx = blockIdx.x * 256 + threadIdx.x;
    if (idx >= total4) return;
    int g = idx & 31;   // float4 group within 128-wide row
    float4 v  = reinterpret_cast<const float4*>(in)[idx];
    float4 sc = reinterpret_cast<const float4*>(scale)[g];
    float4 sh = reinterpret_cast<const float4*>(shift)[g];
    v.x = v.x * sc.x + sh.x;
    v.y = v.y * sc.y + sh.y;
    v.z = v.z * sc.z + sh.z;
    v.w = v.w * sc.w + sh.w;
    reinterpret_cast<float4*>(out)[idx] = v;
}

// ---------------------------------------------------------------------------
// CSR build
// ---------------------------------------------------------------------------
__global__ void edge_count(const int* __restrict__ dst, int* __restrict__ cnt)
{
    int e = blockIdx.x * 256 + threadIdx.x;
    if (e < N_EDGES) atomicAdd(&cnt[dst[e]], 1);
}

__global__ void scan_kernel(const int* __restrict__ cnt, int* __restrict__ row_ptr, int n)
{
    __shared__ int buf[1024];
    __shared__ int carry_s;
    int t = threadIdx.x;
    if (t == 0) carry_s = 0;
    __syncthreads();
    for (int base = 0; base < n; base += 1024) {
        int i = base + t;
        int v = (i < n) ? cnt[i] : 0;
        buf[t] = v;
        __syncthreads();
        for (int off = 1; off < 1024; off <<= 1) {
            int x = (t >= off) ? buf[t - off] : 0;
            __syncthreads();
            buf[t] += x;
            __syncthreads();
        }
        int carry = carry_s;
        if (i < n) row_ptr[i] = carry + buf[t] - v;   // exclusive
        __syncthreads();
        if (t == 1023) carry_s = carry + buf[1023];
        __syncthreads();
    }
    if (t == 0) row_ptr[n] = carry_s;
}

__global__ void edge_fill(const int* __restrict__ src, const int* __restrict__ dst,
                          const int* __restrict__ row_ptr, int* __restrict__ fill,
                          int* __restrict__ col_idx)
{
    int e = blockIdx.x * 256 + threadIdx.x;
    if (e < N_EDGES) {
        int d = dst[e];
        int pos = row_ptr[d] + atomicAdd(&fill[d], 1);
        col_idx[pos] = src[e];
    }
}

// ---------------------------------------------------------------------------
// SpMM mean: agg[i,:] = mean over in-neighbors of H[src,:]. One wave per node,
// float2 per lane (64*2 = 128 cols). Accumulate in registers.
// ---------------------------------------------------------------------------
__global__ __launch_bounds__(256) void spmm_mean(const int* __restrict__ row_ptr,
                                                 const int* __restrict__ col_idx,
                                                 const float* __restrict__ H,
                                                 float* __restrict__ agg)
{
    int node = blockIdx.x * 4 + (threadIdx.x >> 6);
    if (node >= N_NODES) return;
    int lane = threadIdx.x & 63;
    int beg = row_ptr[node];
    int end = row_ptr[node + 1];

    float sx = 0.f, sy = 0.f;
    int e = beg;
    for (; e + 4 <= end; e += 4) {
        int c0 = col_idx[e];
        int c1 = col_idx[e + 1];
        int c2 = col_idx[e + 2];
        int c3 = col_idx[e + 3];
        float2 v0 = *reinterpret_cast<const float2*>(&H[(size_t)c0 * HID + lane * 2]);
        float2 v1 = *reinterpret_cast<const float2*>(&H[(size_t)c1 * HID + lane * 2]);
        float2 v2 = *reinterpret_cast<const float2*>(&H[(size_t)c2 * HID + lane * 2]);
        float2 v3 = *reinterpret_cast<const float2*>(&H[(size_t)c3 * HID + lane * 2]);
        sx += (v0.x + v1.x) + (v2.x + v3.x);
        sy += (v0.y + v1.y) + (v2.y + v3.y);
    }
    for (; e < end; ++e) {
        int c = col_idx[e];
        float2 v = *reinterpret_cast<const float2*>(&H[(size_t)c * HID + lane * 2]);
        sx += v.x; sy += v.y;
    }
    float inv = 1.f / fmaxf((float)(end - beg), 1.f);
    float2 r = {sx * inv, sy * inv};
    *reinterpret_cast<float2*>(&agg[(size_t)node * HID + lane * 2]) = r;
}

// ---------------------------------------------------------------------------
// Final: BN2 apply + L2 row-normalize, in place on d_out. One wave per row.
// ---------------------------------------------------------------------------
__global__ __launch_bounds__(256) void bn_rownorm(float* __restrict__ out,
                                                  const float* __restrict__ scale,
                                                  const float* __restrict__ shift)
{
    int row = blockIdx.x * 4 + (threadIdx.x >> 6);
    if (row >= N_NODES) return;
    int lane = threadIdx.x & 63;
    float2 v  = *reinterpret_cast<const float2*>(&out[(size_t)row * HID + lane * 2]);
    float2 sc = *reinterpret_cast<const float2*>(&scale[lane * 2]);
    float2 sh = *reinterpret_cast<const float2*>(&shift[lane * 2]);
    float y0 = v.x * sc.x + sh.x;
    float y1 = v.y * sc.y + sh.y;
    float ss = y0 * y0 + y1 * y1;
#pragma unroll
    for (int m = 1; m < 64; m <<= 1) ss += __shfl_xor(ss, m);
    float inv = 1.f / fmaxf(sqrtf(ss), 1e-12f);
    float2 r = {y0 * inv, y1 * inv};
    *reinterpret_cast<float2*>(&out[(size_t)row * HID + lane * 2]) = r;
}

// ---------------------------------------------------------------------------
extern "C" void kernel_launch(void* const* d_in, const int* in_sizes, int n_in,
                              void* d_out, int out_size, void* d_ws, size_t ws_size,
                              hipStream_t stream)
{
    const float* x     = (const float*)d_in[0];
    const int*   ei    = (const int*)d_in[1];
    const float* W_in  = (const float*)d_in[2];
    const float* b_in  = (const float*)d_in[3];
    const float* g1    = (const float*)d_in[4];
    const float* be1   = (const float*)d_in[5];
    const float* Wl1   = (const float*)d_in[6];
    const float* bl1   = (const float*)d_in[7];
    const float* Wr1   = (const float*)d_in[8];
    const float* Wl2   = (const float*)d_in[9];
    const float* bl2   = (const float*)d_in[10];
    const float* Wr2   = (const float*)d_in[11];
    const float* Wskip = (const float*)d_in[12];
    const float* bskip = (const float*)d_in[13];
    const float* g2    = (const float*)d_in[14];
    const float* be2   = (const float*)d_in[15];
    float* out = (float*)d_out;

    char* ws = (char*)d_ws;
    const size_t BUF = (size_t)N_NODES * HID * sizeof(float);   // 25,600,000 B
    float* bufA    = (float*)(ws);                //  t / h1
    float* bufB    = (float*)(ws + BUF);          //  h
    float* bufC    = (float*)(ws + 2 * BUF);      //  agg
    char*  zzone   = ws + 3 * BUF;                //  zeroed each call:
    float* stats   = (float*)(zzone);                       // 512 f (bn1, bn2)
    int*   icnt    = (int*)(zzone + 2048);                  // N ints
    int*   fillc   = (int*)(zzone + 2048 + N_NODES * 4);    // N ints
    size_t zsz     = 2048 + (size_t)N_NODES * 4 * 2;
    int*   row_ptr = (int*)(zzone + zsz);                   // N+1 ints
    int*   col_idx = (int*)(zzone + zsz + (N_NODES + 1) * 4);
    float* bnc     = (float*)(zzone + zsz + (N_NODES + 1) * 4 + (size_t)N_EDGES * 4);
    // bnc: scale1[128], shift1[128], scale2[128], shift2[128]

    hipMemsetAsync(zzone, 0, zsz, stream);

    const int* srcp = ei;
    const int* dstp = ei + N_EDGES;

    // ---- CSR build (reused by both SpMMs) ----
    edge_count<<<(N_EDGES + 255) / 256, 256, 0, stream>>>(dstp, icnt);
    scan_kernel<<<1, 1024, 0, stream>>>(icnt, row_ptr, N_NODES);
    edge_fill<<<(N_EDGES + 255) / 256, 256, 0, stream>>>(srcp, dstp, row_ptr, fillc, col_idx);

    const int GB = (N_NODES + 63) / 64;   // 782 gemm blocks

    // ---- layer 0: t = leaky(x @ W_in + b_in), stats for BN1 ----
    gemm_fused<true, true><<<GB, 256, 0, stream>>>(
        N_NODES, 1, x, IN_DIM, nullptr, 0, nullptr, 0,
        W_in, nullptr, nullptr, b_in, nullptr, bufA, stats);
    bn_params<<<1, 128, 0, stream>>>(stats, g1, be1, bnc, bnc + 128, 1.f / N_NODES);
    bn_apply<<<(N_NODES * HID / 4 + 255) / 256, 256, 0, stream>>>(
        bufA, bufB, bnc, bnc + 128, N_NODES * HID / 4);

    // ---- sage1: h1 = leaky(mean_agg(h) @ Wl1 + bl1 + h @ Wr1) ----
    spmm_mean<<<(N_NODES + 3) / 4, 256, 0, stream>>>(row_ptr, col_idx, bufB, bufC);
    gemm_fused<true, false><<<GB, 256, 0, stream>>>(
        N_NODES, 2, bufC, HID, bufB, HID, nullptr, 0,
        Wl1, Wr1, nullptr, bl1, nullptr, bufA, nullptr);

    // ---- sage2 + skip: out_pre = mean_agg(h1)@Wl2 + h1@Wr2 + h@Wskip + bl2 + bskip ----
    spmm_mean<<<(N_NODES + 3) / 4, 256, 0, stream>>>(row_ptr, col_idx, bufA, bufC);
    gemm_fused<false, true><<<GB, 256, 0, stream>>>(
        N_NODES, 3, bufC, HID, bufA, HID, bufB, HID,
        Wl2, Wr2, Wskip, bl2, bskip, out, stats + 256);

    // ---- BN2 + row normalize (in place on d_out) ----
    bn_params<<<1, 128, 0, stream>>>(stats + 256, g2, be2, bnc + 256, bnc + 384, 1.f / N_NODES);
    bn_rownorm<<<(N_NODES + 3) / 4, 256, 0, stream>>>(out, bnc + 256, bnc + 384);
}

// Round 2
// 268.486 us; speedup vs baseline: 1.9635x; 1.9635x over previous
//
#include <hip/hip_runtime.h>
#include <math.h>

#define N_NODES 50000
#define N_EDGES 800000
#define IN_DIM 256
#define HID 128
#define ZPITCH 384   // [agg:0..128 | h:128..256 | h1:256..384]

typedef unsigned short u16;
typedef u16 u16x8 __attribute__((ext_vector_type(8)));
typedef u16 u16x2 __attribute__((ext_vector_type(2)));
typedef __bf16 bf16x8 __attribute__((ext_vector_type(8)));
typedef float f32x4 __attribute__((ext_vector_type(4)));

union F8 { u16x8 u; bf16x8 h; };

__device__ __forceinline__ u16 f2b(float f) {
    unsigned u = __builtin_bit_cast(unsigned, f);
    u = (u + 0x7FFFu + ((u >> 16) & 1u)) >> 16;   // RNE
    return (u16)u;
}
__device__ __forceinline__ float b2f(u16 h) {
    unsigned u = ((unsigned)h) << 16;
    return __builtin_bit_cast(float, u);
}

// ---------------------------------------------------------------------------
// Unified bf16 MFMA GEMM: C[M,128] = act(A[M,K] @ Wf + bias0 (+bias1))
// A: bf16 row-major with pitch P. Wf: fragment-ordered bf16
//   (elem offset ((c*8 + j)*64 + lane)*8 + i  <=>  W[c*32 + (lane>>4)*8 + i][16j + (lane&15)])
// Block = 256 thr = 4 waves, each wave 32 rows (2 M-frags) x 128 cols (8 N-frags).
// LDS-free: A frags gathered per-lane (full 64B line per 4 lanes), B frags linear from L2.
// ---------------------------------------------------------------------------
template<int LEAKY, int STATS, int OUT_BF16>
__global__ __launch_bounds__(256) void gemm_mfma(
    int M, const u16* __restrict__ A, int P, int K,
    const u16* __restrict__ Wf,
    const float* __restrict__ bias0, const float* __restrict__ bias1,
    void* __restrict__ Cout, int CP,
    float* __restrict__ stats)
{
    const int t   = threadIdx.x;
    const int w   = t >> 6;
    const int l   = t & 63;
    const int l15 = l & 15;
    const int lg  = l >> 4;
    const int rb  = blockIdx.x * 128 + w * 32;

    int r0 = rb + l15;
    int r1 = r0 + 16;
    int r0c = r0 < M ? r0 : M - 1;
    int r1c = r1 < M ? r1 : M - 1;
    const u16* pa0 = A + (size_t)r0c * P + lg * 8;
    const u16* pa1 = A + (size_t)r1c * P + lg * 8;
    const u16* pb  = Wf + l * 8;

    f32x4 acc[2][8];
#pragma unroll
    for (int m = 0; m < 2; ++m)
#pragma unroll
        for (int j = 0; j < 8; ++j) acc[m][j] = 0.0f;

    F8 a0, a1, b[8];
    a0.u = *(const u16x8*)pa0;
    a1.u = *(const u16x8*)pa1;
#pragma unroll
    for (int j = 0; j < 8; ++j) b[j].u = *(const u16x8*)(pb + j * 512);

    const int NC = K >> 5;
    for (int c = 1; c < NC; ++c) {
        F8 na0, na1, nb[8];
        na0.u = *(const u16x8*)(pa0 + c * 32);
        na1.u = *(const u16x8*)(pa1 + c * 32);
#pragma unroll
        for (int j = 0; j < 8; ++j) nb[j].u = *(const u16x8*)(pb + c * 4096 + j * 512);
#pragma unroll
        for (int j = 0; j < 8; ++j) {
            acc[0][j] = __builtin_amdgcn_mfma_f32_16x16x32_bf16(a0.h, b[j].h, acc[0][j], 0, 0, 0);
            acc[1][j] = __builtin_amdgcn_mfma_f32_16x16x32_bf16(a1.h, b[j].h, acc[1][j], 0, 0, 0);
        }
        a0 = na0; a1 = na1;
#pragma unroll
        for (int j = 0; j < 8; ++j) b[j] = nb[j];
    }
#pragma unroll
    for (int j = 0; j < 8; ++j) {
        acc[0][j] = __builtin_amdgcn_mfma_f32_16x16x32_bf16(a0.h, b[j].h, acc[0][j], 0, 0, 0);
        acc[1][j] = __builtin_amdgcn_mfma_f32_16x16x32_bf16(a1.h, b[j].h, acc[1][j], 0, 0, 0);
    }

    // epilogue: bias, leaky, store (C/D layout: col = 16j + (l&15), row = rb + m*16 + (l>>4)*4 + reg)
    float bias_j[8];
#pragma unroll
    for (int j = 0; j < 8; ++j) {
        float bb = bias0[16 * j + l15];
        if (bias1) bb += bias1[16 * j + l15];
        bias_j[j] = bb;
    }

    float csum[8], csq[8];
#pragma unroll
    for (int j = 0; j < 8; ++j) { csum[j] = 0.f; csq[j] = 0.f; }

#pragma unroll
    for (int m = 0; m < 2; ++m) {
        int rbase = rb + m * 16 + lg * 4;
#pragma unroll
        for (int r = 0; r < 4; ++r) {
            int row = rbase + r;
            bool ok = row < M;
#pragma unroll
            for (int j = 0; j < 8; ++j) {
                float y = acc[m][j][r] + bias_j[j];
                if (LEAKY) y = (y >= 0.f) ? y : 0.2f * y;
                if (ok) {
                    if (OUT_BF16)
                        ((u16*)Cout)[(size_t)row * CP + 16 * j + l15] = f2b(y);
                    else
                        ((float*)Cout)[(size_t)row * CP + 16 * j + l15] = y;
                    if (STATS) { csum[j] += y; csq[j] += y * y; }
                }
            }
        }
    }

    if (STATS) {
        __shared__ float sred[256];
        sred[t] = 0.f;
        __syncthreads();
#pragma unroll
        for (int j = 0; j < 8; ++j) {
            float s = csum[j];
            float q = csq[j];
            s += __shfl_xor(s, 16); s += __shfl_xor(s, 32);
            q += __shfl_xor(q, 16); q += __shfl_xor(q, 32);
            if (lg == 0) {
                atomicAdd(&sred[16 * j + l15], s);
                atomicAdd(&sred[128 + 16 * j + l15], q);
            }
        }
        __syncthreads();
        atomicAdd(&stats[t], sred[t]);
    }
}

// ---------------------------------------------------------------------------
// Conversions
// ---------------------------------------------------------------------------
__global__ __launch_bounds__(256) void conv_x(const float* __restrict__ x,
                                              u16* __restrict__ xb, int n8)
{
    int i = blockIdx.x * 256 + threadIdx.x;
    if (i >= n8) return;
    float4 f0 = reinterpret_cast<const float4*>(x)[i * 2];
    float4 f1 = reinterpret_cast<const float4*>(x)[i * 2 + 1];
    u16x8 o;
    o[0] = f2b(f0.x); o[1] = f2b(f0.y); o[2] = f2b(f0.z); o[3] = f2b(f0.w);
    o[4] = f2b(f1.x); o[5] = f2b(f1.y); o[6] = f2b(f1.z); o[7] = f2b(f1.w);
    reinterpret_cast<u16x8*>(xb)[i] = o;
}

// weight -> fragment-ordered bf16 (stacked sources, each rows_each rows of 128 cols)
__global__ __launch_bounds__(256) void conv_w(const float* s0, const float* s1, const float* s2,
                                              int rows_each, u16* __restrict__ dst, int nchunks)
{
    int tid = blockIdx.x * 256 + threadIdx.x;
    if (tid >= nchunks * 512) return;
    int c   = tid >> 9;
    int j   = (tid >> 6) & 7;
    int l   = tid & 63;
    int l15 = l & 15, lg = l >> 4;

    int srow0 = c * 32;
    int si    = srow0 / rows_each;
    const float* S = (si == 0) ? s0 : (si == 1) ? s1 : s2;
    int rbase = srow0 - si * rows_each + lg * 8;
    int col   = 16 * j + l15;

    u16x8 o;
#pragma unroll
    for (int i = 0; i < 8; ++i) o[i] = f2b(S[(size_t)(rbase + i) * HID + col]);
    reinterpret_cast<u16x8*>(dst)[tid] = o;
}

// ---------------------------------------------------------------------------
// BatchNorm
// ---------------------------------------------------------------------------
__global__ void bn_params(const float* __restrict__ stats,
                          const float* __restrict__ gamma,
                          const float* __restrict__ beta,
                          float* __restrict__ scale,
                          float* __restrict__ shift, float invn)
{
    int j = threadIdx.x;
    float mean = stats[j] * invn;
    float var  = stats[128 + j] * invn - mean * mean;
    var = fmaxf(var, 0.f);
    float sc = gamma[j] / sqrtf(var + 1e-5f);
    scale[j] = sc;
    shift[j] = beta[j] - mean * sc;
}

// in-place BN apply on bf16 h (pitch ZPITCH, col offset 128)
__global__ __launch_bounds__(256) void bn_apply(u16* __restrict__ Z,
                                                const float* __restrict__ scale,
                                                const float* __restrict__ shift)
{
    int tid = blockIdx.x * 256 + threadIdx.x;
    if (tid >= N_NODES * 16) return;
    int row = tid >> 4;
    int g   = tid & 15;
    u16* p = Z + (size_t)row * ZPITCH + 128 + g * 8;
    u16x8 v = *reinterpret_cast<u16x8*>(p);
    u16x8 o;
#pragma unroll
    for (int e = 0; e < 8; ++e)
        o[e] = f2b(b2f(v[e]) * scale[g * 8 + e] + shift[g * 8 + e]);
    *reinterpret_cast<u16x8*>(p) = o;
}

// ---------------------------------------------------------------------------
// CSR build (count -> hierarchical scan -> fill)
// ---------------------------------------------------------------------------
__global__ __launch_bounds__(256) void edge_count(const int* __restrict__ dst, int* __restrict__ cnt)
{
    int e = blockIdx.x * 256 + threadIdx.x;
    if (e < N_EDGES) atomicAdd(&cnt[dst[e]], 1);
}

__global__ __launch_bounds__(256) void scan_block(const int* __restrict__ cnt,
                                                  int* __restrict__ excl,
                                                  int* __restrict__ bsum, int n)
{
    __shared__ int sh[256];
    int t = threadIdx.x;
    int i = blockIdx.x * 256 + t;
    int v = (i < n) ? cnt[i] : 0;
    sh[t] = v;
    __syncthreads();
#pragma unroll
    for (int off = 1; off < 256; off <<= 1) {
        int x = (t >= off) ? sh[t - off] : 0;
        __syncthreads();
        sh[t] += x;
        __syncthreads();
    }
    if (i < n) excl[i] = sh[t] - v;
    if (t == 255) bsum[blockIdx.x] = sh[255];
}

__global__ __launch_bounds__(256) void scan_bsum(int* __restrict__ bsum, int nb)
{
    __shared__ int sh[256];
    int t = threadIdx.x;
    int v = (t < nb) ? bsum[t] : 0;
    sh[t] = v;
    __syncthreads();
#pragma unroll
    for (int off = 1; off < 256; off <<= 1) {
        int x = (t >= off) ? sh[t - off] : 0;
        __syncthreads();
        sh[t] += x;
        __syncthreads();
    }
    if (t < nb) bsum[t] = sh[t] - v;   // exclusive
}

__global__ __launch_bounds__(256) void scan_add(int* __restrict__ row_ptr,
                                                const int* __restrict__ bsum, int n)
{
    int i = blockIdx.x * 256 + threadIdx.x;
    if (i < n) row_ptr[i] += bsum[i >> 8];
    if (i == 0) row_ptr[n] = N_EDGES;
}

__global__ __launch_bounds__(256) void edge_fill(const int* __restrict__ src,
                                                 const int* __restrict__ dst,
                                                 const int* __restrict__ row_ptr,
                                                 int* __restrict__ fill,
                                                 int* __restrict__ col_idx)
{
    int e = blockIdx.x * 256 + threadIdx.x;
    if (e < N_EDGES) {
        int d = dst[e];
        int pos = row_ptr[d] + atomicAdd(&fill[d], 1);
        col_idx[pos] = src[e];
    }
}

// ---------------------------------------------------------------------------
// SpMM mean over bf16 rows in Z (read col offset coff, write col 0).
// One wave per node; lane holds 2 cols (ushort2 = 4B/lane, 256B/row).
// ---------------------------------------------------------------------------
__global__ __launch_bounds__(256) void spmm_mean(const int* __restrict__ row_ptr,
                                                 const int* __restrict__ col_idx,
                                                 const u16* __restrict__ Z_in, // Z + coff
                                                 u16* __restrict__ Z_out)      // Z + 0
{
    int node = blockIdx.x * 4 + (threadIdx.x >> 6);
    if (node >= N_NODES) return;
    int lane = threadIdx.x & 63;
    int beg = row_ptr[node];
    int end = row_ptr[node + 1];

    float sx = 0.f, sy = 0.f;
    int e = beg;
    for (; e + 4 <= end; e += 4) {
        int c0 = col_idx[e], c1 = col_idx[e + 1], c2 = col_idx[e + 2], c3 = col_idx[e + 3];
        u16x2 v0 = *reinterpret_cast<const u16x2*>(Z_in + (size_t)c0 * ZPITCH + lane * 2);
        u16x2 v1 = *reinterpret_cast<const u16x2*>(Z_in + (size_t)c1 * ZPITCH + lane * 2);
        u16x2 v2 = *reinterpret_cast<const u16x2*>(Z_in + (size_t)c2 * ZPITCH + lane * 2);
        u16x2 v3 = *reinterpret_cast<const u16x2*>(Z_in + (size_t)c3 * ZPITCH + lane * 2);
        sx += (b2f(v0[0]) + b2f(v1[0])) + (b2f(v2[0]) + b2f(v3[0]));
        sy += (b2f(v0[1]) + b2f(v1[1])) + (b2f(v2[1]) + b2f(v3[1]));
    }
    for (; e < end; ++e) {
        int c = col_idx[e];
        u16x2 v = *reinterpret_cast<const u16x2*>(Z_in + (size_t)c * ZPITCH + lane * 2);
        sx += b2f(v[0]); sy += b2f(v[1]);
    }
    float inv = 1.f / fmaxf((float)(end - beg), 1.f);
    u16x2 r; r[0] = f2b(sx * inv); r[1] = f2b(sy * inv);
    *reinterpret_cast<u16x2*>(Z_out + (size_t)node * ZPITCH + lane * 2) = r;
}

// ---------------------------------------------------------------------------
// Final: BN2 apply + L2 row-normalize, in place on d_out (fp32). One wave/row.
// ---------------------------------------------------------------------------
__global__ __launch_bounds__(256) void bn_rownorm(float* __restrict__ out,
                                                  const float* __restrict__ scale,
                                                  const float* __restrict__ shift)
{
    int row = blockIdx.x * 4 + (threadIdx.x >> 6);
    if (row >= N_NODES) return;
    int lane = threadIdx.x & 63;
    float2 v  = *reinterpret_cast<const float2*>(&out[(size_t)row * HID + lane * 2]);
    float2 sc = *reinterpret_cast<const float2*>(&scale[lane * 2]);
    float2 sh = *reinterpret_cast<const float2*>(&shift[lane * 2]);
    float y0 = v.x * sc.x + sh.x;
    float y1 = v.y * sc.y + sh.y;
    float ss = y0 * y0 + y1 * y1;
#pragma unroll
    for (int m = 1; m < 64; m <<= 1) ss += __shfl_xor(ss, m);
    float inv = 1.f / fmaxf(sqrtf(ss), 1e-12f);
    float2 r = {y0 * inv, y1 * inv};
    *reinterpret_cast<float2*>(&out[(size_t)row * HID + lane * 2]) = r;
}

// ---------------------------------------------------------------------------
extern "C" void kernel_launch(void* const* d_in, const int* in_sizes, int n_in,
                              void* d_out, int out_size, void* d_ws, size_t ws_size,
                              hipStream_t stream)
{
    const float* x     = (const float*)d_in[0];
    const int*   ei    = (const int*)d_in[1];
    const float* W_in  = (const float*)d_in[2];
    const float* b_in  = (const float*)d_in[3];
    const float* g1    = (const float*)d_in[4];
    const float* be1   = (const float*)d_in[5];
    const float* Wl1   = (const float*)d_in[6];
    const float* bl1   = (const float*)d_in[7];
    const float* Wr1   = (const float*)d_in[8];
    const float* Wl2   = (const float*)d_in[9];
    const float* bl2   = (const float*)d_in[10];
    const float* Wr2   = (const float*)d_in[11];
    const float* Wskip = (const float*)d_in[12];
    const float* bskip = (const float*)d_in[13];
    const float* g2    = (const float*)d_in[14];
    const float* be2   = (const float*)d_in[15];
    float* out = (float*)d_out;

    char* ws = (char*)d_ws;
    u16*  xb = (u16*)ws;                                    // 25,600,000 B
    u16*  Z  = (u16*)(ws + 25600000);                       // 38,400,000 B
    char* zzone = ws + 64000000;
    float* stats = (float*)zzone;                           // 512 f
    int*   icnt  = (int*)(zzone + 2048);                    // N
    int*   fillc = (int*)(zzone + 2048 + N_NODES * 4);      // N
    size_t zsz   = 2048 + (size_t)N_NODES * 8;              // 402,048 B
    int*   row_ptr = (int*)(zzone + zsz);                   // N+1
    int*   bsum    = (int*)(zzone + zsz + 200064);          // 256
    int*   col_idx = (int*)(zzone + zsz + 200064 + 1024);   // E
    float* bnc     = (float*)(zzone + zsz + 200064 + 1024 + (size_t)N_EDGES * 4);
    // weight stacks (bf16 frag-ordered): W_in (8 chunks), [Wl1;Wr1] (8), [Wl2;Wskip;Wr2] (12)
    u16* WfA = (u16*)((char*)bnc + 2048);
    u16* WfB = WfA + 8 * 4096;
    u16* WfC = WfB + 8 * 4096;

    hipMemsetAsync(zzone, 0, zsz, stream);

    const int* srcp = ei;
    const int* dstp = ei + N_EDGES;

    // conversions
    conv_x<<<(N_NODES * IN_DIM / 8 + 255) / 256, 256, 0, stream>>>(x, xb, N_NODES * IN_DIM / 8);
    conv_w<<<16, 256, 0, stream>>>(W_in, nullptr, nullptr, 256, WfA, 8);
    conv_w<<<16, 256, 0, stream>>>(Wl1, Wr1, nullptr, 128, WfB, 8);
    conv_w<<<24, 256, 0, stream>>>(Wl2, Wskip, Wr2, 128, WfC, 12);

    // CSR build
    const int NB = (N_NODES + 255) / 256;   // 196
    edge_count<<<(N_EDGES + 255) / 256, 256, 0, stream>>>(dstp, icnt);
    scan_block<<<NB, 256, 0, stream>>>(icnt, row_ptr, bsum, N_NODES);
    scan_bsum<<<1, 256, 0, stream>>>(bsum, NB);
    scan_add<<<NB, 256, 0, stream>>>(row_ptr, bsum, N_NODES);
    edge_fill<<<(N_EDGES + 255) / 256, 256, 0, stream>>>(srcp, dstp, row_ptr, fillc, col_idx);

    const int GB = (N_NODES + 127) / 128;   // 391

    // layer 0: t = leaky(x @ W_in + b_in) -> Z[:,128:256] bf16, stats1
    gemm_mfma<1, 1, 1><<<GB, 256, 0, stream>>>(
        N_NODES, xb, IN_DIM, 256, WfA, b_in, nullptr, Z + 128, ZPITCH, stats);
    bn_params<<<1, 128, 0, stream>>>(stats, g1, be1, bnc, bnc + 128, 1.f / N_NODES);
    bn_apply<<<(N_NODES * 16 + 255) / 256, 256, 0, stream>>>(Z, bnc, bnc + 128);

    // sage1: h1 = leaky([agg1|h] @ [Wl1;Wr1] + bl1) -> Z[:,256:384]
    spmm_mean<<<(N_NODES + 3) / 4, 256, 0, stream>>>(row_ptr, col_idx, Z + 128, Z);
    gemm_mfma<1, 0, 1><<<GB, 256, 0, stream>>>(
        N_NODES, Z, ZPITCH, 256, WfB, bl1, nullptr, Z + 256, ZPITCH, nullptr);

    // sage2 + skip: out_pre = [agg2|h|h1] @ [Wl2;Wskip;Wr2] + bl2 + bskip -> d_out fp32, stats2
    spmm_mean<<<(N_NODES + 3) / 4, 256, 0, stream>>>(row_ptr, col_idx, Z + 256, Z);
    gemm_mfma<0, 1, 0><<<GB, 256, 0, stream>>>(
        N_NODES, Z, ZPITCH, 384, WfC, bl2, bskip, out, HID, stats + 256);

    // BN2 + row normalize
    bn_params<<<1, 128, 0, stream>>>(stats + 256, g2, be2, bnc + 256, bnc + 384, 1.f / N_NODES);
    bn_rownorm<<<(N_NODES + 3) / 4, 256, 0, stream>>>(out, bnc + 256, bnc + 384);
}